// Round 10
// baseline (3946.996 us; speedup 1.0000x reference)
//
#include <hip/hip_runtime.h>
#include <hip/hip_bf16.h>

#define HID   1000
#define DICT  4811
#define TT    44
#define BB    256
#define G4    4000
#define G4P   4096
#define K1P   2048
#define K2P   6912
#define HP    1024
#define Z2_H2 4864
#define Z2_H1 5888
#define PD    3
#define GPART ((long long)BB * G4P)

typedef __attribute__((ext_vector_type(8))) short short8;
typedef __attribute__((ext_vector_type(4))) float f32x4;

__device__ __forceinline__ short f2b(float f) {
    unsigned u = __float_as_uint(f);
    unsigned r = (u + 0x7FFFu + ((u >> 16) & 1u)) >> 16;
    return (short)r;
}

__device__ __forceinline__ void gload16(const void* g, const short* l) {
    __builtin_amdgcn_global_load_lds(
        (const __attribute__((address_space(1))) unsigned int*)g,
        (__attribute__((address_space(3))) unsigned int*)l, 16, 0, 0);
}

// ---------------- prep kernels ----------------
__global__ void prep_w1i(const float* __restrict__ wih1, const float* __restrict__ whh1,
                         short* __restrict__ w) {
    for (size_t i = (size_t)blockIdx.x * blockDim.x + threadIdx.x; i < (size_t)G4P * K1P;
         i += (size_t)gridDim.x * blockDim.x) {
        int n = (int)(i >> 11), j = (int)(i & 2047);
        int h = n >> 2, g = n & 3;
        float v = 0.f;
        if (h < HID) {
            int r = g * HID + h;
            if (j < HID) v = wih1[(size_t)r * 2000 + j];
            else if (j >= 1024 && j < 1024 + HID) {
                int jj = j - 1024;
                v = wih1[(size_t)r * 2000 + HID + jj] + whh1[(size_t)r * HID + jj];
            }
        }
        w[i] = f2b(v);
    }
}

__global__ void prep_w2p(const float* __restrict__ wih2, const float* __restrict__ whh2,
                         short* __restrict__ w) {
    int n = blockIdx.y;
    int j = blockIdx.x * 256 + threadIdx.x;
    float v = 0.f;
    if (n < G4) {
        if (j < DICT) v = wih2[(size_t)n * 6811 + j];
        else if (j >= Z2_H2 && j < Z2_H2 + HID) {
            int jj = j - Z2_H2;
            v = wih2[(size_t)n * 6811 + DICT + jj] + whh2[(size_t)n * HID + jj];
        } else if (j >= Z2_H1 && j < Z2_H1 + HID) {
            int jj = j - Z2_H1;
            v = wih2[(size_t)n * 6811 + DICT + HID + jj];
        }
    }
    w[(size_t)n * K2P + j] = f2b(v);
}

__global__ void prep_outwp(const float* __restrict__ outw, short* __restrict__ w) {
    int n = blockIdx.y;
    int j = blockIdx.x * 256 + threadIdx.x;
    float v = (n < DICT && j < HID) ? outw[(size_t)n * HID + j] : 0.f;
    w[(size_t)n * HP + j] = f2b(v);
}

__global__ void prep_cvt(const float* __restrict__ src, short* __restrict__ dst, size_t n) {
    for (size_t i = (size_t)blockIdx.x * blockDim.x + threadIdx.x; i < n;
         i += (size_t)gridDim.x * blockDim.x)
        dst[i] = f2b(src[i]);
}

__global__ void prep_addv(const float* __restrict__ a, const float* __restrict__ b,
                          float* __restrict__ dst, int n) {
    int i = blockIdx.x * blockDim.x + threadIdx.x;
    if (i < n) dst[i] = a[i] + b[i];
}

__global__ void prep_biasi(const float* __restrict__ bi, const float* __restrict__ bh,
                           float* __restrict__ dst) {
    int n = blockIdx.x * 256 + threadIdx.x;
    if (n >= 4096) return;
    int h = n >> 2, g = n & 3;
    dst[n] = (h < HID) ? bi[g * HID + h] + bh[g * HID + h] : 0.f;
}

__global__ void init_vec(const float* __restrict__ src, short* __restrict__ dst, int ld) {
    int i = blockIdx.x * blockDim.x + threadIdx.x;
    if (i >= BB * HID) return;
    int b = i / HID, h = i % HID;
    dst[(size_t)b * ld + h] = f2b(src[i]);
}

// ---------------- xp projection GEMM (verified, runs once) ----------------
template <int EPI, int AF32>
__global__ __launch_bounds__(256) void gemm_nt(
    const void* __restrict__ Ap, int lda,
    const short* __restrict__ Bp, int ldb,
    const float* __restrict__ bias,
    void* __restrict__ Cp, long long partStride, int ldc,
    int M, int N, int Kvalid)
{
    __shared__ short As[64][40];
    __shared__ short Bs[64][40];
    const int tid  = threadIdx.x;
    const int lane = tid & 63;
    const int wave = tid >> 6;
    const int wm = wave >> 1, wn = wave & 1;
    const int tm = blockIdx.y * 64, tn = blockIdx.x * 64;
    const int srow = tid >> 2;
    const int scol = (tid & 3) * 8;

    const int nk = (Kvalid + 31) >> 5;
    const int s0 = (int)(((long long)nk * blockIdx.z) / gridDim.z);
    const int s1 = (int)(((long long)nk * (blockIdx.z + 1)) / gridDim.z);

    const int arow = tm + srow;
    const int brow = tn + srow;
    const bool bvalid = brow < N;

    auto loadA = [&](int ks) -> short8 {
        int k = (ks << 5) + scol;
        short8 r = {0, 0, 0, 0, 0, 0, 0, 0};
        if (k + 8 <= Kvalid) {
            if (AF32) {
                const f32x4* p = (const f32x4*)((const float*)Ap + (size_t)arow * lda + k);
                f32x4 u0 = p[0], u1 = p[1];
                r[0] = f2b(u0[0]); r[1] = f2b(u0[1]); r[2] = f2b(u0[2]); r[3] = f2b(u0[3]);
                r[4] = f2b(u1[0]); r[5] = f2b(u1[1]); r[6] = f2b(u1[2]); r[7] = f2b(u1[3]);
            } else {
                r = *(const short8*)((const short*)Ap + (size_t)arow * lda + k);
            }
        }
        return r;
    };
    auto loadB = [&](int ks) -> short8 {
        int k = (ks << 5) + scol;
        short8 r = {0, 0, 0, 0, 0, 0, 0, 0};
        if (bvalid && (k + 8 <= Kvalid))
            r = *(const short8*)(Bp + (size_t)brow * ldb + k);
        return r;
    };

    f32x4 acc[2][2];
    for (int a = 0; a < 2; ++a)
        for (int b = 0; b < 2; ++b)
            acc[a][b] = (f32x4){0.f, 0.f, 0.f, 0.f};

    short8 ra = loadA(s0), rb = loadB(s0);
    *(short8*)&As[srow][scol] = ra;
    *(short8*)&Bs[srow][scol] = rb;
    __syncthreads();

    const int kg = (lane >> 4) * 8;
    const int fr = lane & 15;

    for (int s = s0; s < s1; ++s) {
        short8 a0 = *(short8*)&As[wm * 32 + fr][kg];
        short8 a1 = *(short8*)&As[wm * 32 + 16 + fr][kg];
        short8 b0 = *(short8*)&Bs[wn * 32 + fr][kg];
        short8 b1 = *(short8*)&Bs[wn * 32 + 16 + fr][kg];
        short8 na, nb;
        if (s + 1 < s1) { na = loadA(s + 1); nb = loadB(s + 1); }
        acc[0][0] = __builtin_amdgcn_mfma_f32_16x16x32_bf16(a0, b0, acc[0][0], 0, 0, 0);
        acc[0][1] = __builtin_amdgcn_mfma_f32_16x16x32_bf16(a0, b1, acc[0][1], 0, 0, 0);
        acc[1][0] = __builtin_amdgcn_mfma_f32_16x16x32_bf16(a1, b0, acc[1][0], 0, 0, 0);
        acc[1][1] = __builtin_amdgcn_mfma_f32_16x16x32_bf16(a1, b1, acc[1][1], 0, 0, 0);
        __syncthreads();
        if (s + 1 < s1) {
            *(short8*)&As[srow][scol] = na;
            *(short8*)&Bs[srow][scol] = nb;
        }
        __syncthreads();
    }

    float* Cf = (float*)Cp + (size_t)partStride * blockIdx.z;
    for (int mi = 0; mi < 2; ++mi)
        for (int ni = 0; ni < 2; ++ni) {
            int col = tn + wn * 32 + ni * 16 + (lane & 15);
            if (col >= N) continue;
            float bv = bias ? bias[col] : 0.f;
            int row0 = tm + wm * 32 + mi * 16 + ((lane >> 4) << 2);
            f32x4 v = acc[mi][ni];
            for (int j = 0; j < 4; ++j) {
                int row = row0 + j;
                float val = v[j] + bv;
                if (EPI == 0) {
                    Cf[(size_t)row * ldc + col] = val;
                } else {
                    int b = row / TT, t = row % TT;
                    ((short*)Cp)[((size_t)t * BB + b) * ldc + col] = f2b(val);
                }
            }
        }
}

// ---------------- gates1 GEMM + in-block LSTM cell (r9-verified), frag-pipelined ------
__global__ __launch_bounds__(256) void gates1F(
    const short* __restrict__ xp_t,
    const short* __restrict__ h1m,
    const short* __restrict__ w1i,
    const f32x4* __restrict__ bias4,
    float* __restrict__ c1,
    short* __restrict__ zh1,
    short* __restrict__ h1nxt)
{
    __shared__ __align__(16) short smem[PD][4096];
    const int tid  = threadIdx.x;
    const int lane = tid & 63;
    const int w    = tid >> 6;
    const int wm = w >> 1, wn = w & 1;
    const int tm = blockIdx.y * 64;
    const int tn = blockIdx.x * 64;
    const int nk = K1P / 32;                          // 64

    const int rA = tid >> 2, sl = tid & 3;
    const int swz = (sl ^ ((rA >> 1) & 3)) << 3;
    const size_t aoff = (size_t)(tm + rA) * HP + (size_t)swz;
    const size_t boff = (size_t)(tn + rA) * K1P + (size_t)swz;

    auto stage = [&](int buf, int s) {
        const int k0 = s << 5;
        const short* As = (k0 < 1024) ? xp_t : h1m;
        const short* l = &smem[buf][0];
        gload16(As + k0 + aoff, l + tid * 8);
        gload16(w1i + k0 + boff, l + 2048 + tid * 8);
    };

    const int fr = lane & 15;
    const int kg = lane >> 4;
    int aRd[2], bRd[2];
    #pragma unroll
    for (int mi = 0; mi < 2; ++mi) {
        int row = wm * 32 + mi * 16 + fr;
        aRd[mi] = row * 32 + ((kg ^ ((row >> 1) & 3)) << 3);
    }
    #pragma unroll
    for (int ni = 0; ni < 2; ++ni) {
        int row = wn * 32 + ni * 16 + fr;
        bRd[ni] = 2048 + row * 32 + ((kg ^ ((row >> 1) & 3)) << 3);
    }

    f32x4 acc[2][2];
    #pragma unroll
    for (int a = 0; a < 2; ++a)
        #pragma unroll
        for (int b = 0; b < 2; ++b)
            acc[a][b] = (f32x4){0.f, 0.f, 0.f, 0.f};

    #pragma unroll
    for (int i = 0; i < PD; ++i)
        if (i < nk) stage(i, i);

    // preload frags for step 0
    asm volatile("s_waitcnt vmcnt(4)" ::: "memory");   // nk=64 >= PD
    __builtin_amdgcn_s_barrier();
    short8 af[2], bf[2];
    {
        const short* bp = &smem[0][0];
        #pragma unroll
        for (int i = 0; i < 2; ++i) af[i] = *(const short8*)(bp + aRd[i]);
        #pragma unroll
        for (int i = 0; i < 2; ++i) bf[i] = *(const short8*)(bp + bRd[i]);
    }

    int buf = 0;
    for (int s = 0; s < nk; ++s) {
        asm volatile("s_waitcnt lgkmcnt(0)" ::: "memory");   // my reads from smem[buf] done
        __builtin_amdgcn_sched_barrier(0);
        __builtin_amdgcn_s_barrier();                        // all waves done reading smem[buf]
        if (s + PD < nk) stage(buf, s + PD);
        const int nbuf = (buf + 1 == PD) ? 0 : buf + 1;
        short8 naf[2], nbf[2];
        const bool more = (s + 1 < nk);
        if (more) {
            int ahead = nk - 1 - (s + 1); if (ahead > PD - 1) ahead = PD - 1;
            if (ahead >= 2)      asm volatile("s_waitcnt vmcnt(4)" ::: "memory");
            else if (ahead == 1) asm volatile("s_waitcnt vmcnt(2)" ::: "memory");
            else                 asm volatile("s_waitcnt vmcnt(0)" ::: "memory");
            __builtin_amdgcn_s_barrier();                    // smem[nbuf] staged
            const short* np = &smem[nbuf][0];
            #pragma unroll
            for (int i = 0; i < 2; ++i) naf[i] = *(const short8*)(np + aRd[i]);
            #pragma unroll
            for (int i = 0; i < 2; ++i) nbf[i] = *(const short8*)(np + bRd[i]);
            __builtin_amdgcn_sched_barrier(0);               // reads issued before MFMAs
        }
        #pragma unroll
        for (int mi = 0; mi < 2; ++mi)
            #pragma unroll
            for (int ni = 0; ni < 2; ++ni)
                acc[mi][ni] = __builtin_amdgcn_mfma_f32_16x16x32_bf16(af[mi], bf[ni], acc[mi][ni], 0, 0, 0);
        if (more) {
            #pragma unroll
            for (int i = 0; i < 2; ++i) { af[i] = naf[i]; bf[i] = nbf[i]; }
        }
        buf = nbuf;
    }

    // epilogue: acc -> LDS [64][68] f32, then LSTM cell (single writer)
    float* gl = (float*)&smem[0][0];
    #pragma unroll
    for (int mi = 0; mi < 2; ++mi)
        #pragma unroll
        for (int ni = 0; ni < 2; ++ni) {
            int row = wm * 32 + mi * 16 + kg * 4;
            int col = wn * 32 + ni * 16 + fr;
            #pragma unroll
            for (int j = 0; j < 4; ++j)
                gl[(row + j) * 68 + col] = acc[mi][ni][j];
        }
    __syncthreads();

    const int b_loc = tid & 63;
    const int b_g = tm + b_loc;
    #pragma unroll
    for (int q = 0; q < 4; ++q) {
        int h_loc = (tid >> 6) * 4 + q;
        int h_g = blockIdx.x * 16 + h_loc;
        if (h_g >= HID) continue;
        f32x4 g4 = *(const f32x4*)(gl + b_loc * 68 + h_loc * 4);
        g4 += bias4[h_g];
        float ii = 1.f / (1.f + expf(-g4[0]));
        float ff = 1.f / (1.f + expf(-g4[1]));
        float tg = tanhf(g4[2]);
        float oo = 1.f / (1.f + expf(-g4[3]));
        float cn = ff * c1[(size_t)b_g * HID + h_g] + ii * tg;
        c1[(size_t)b_g * HID + h_g] = cn;
        short hb = f2b(oo * tanhf(cn));
        zh1[(size_t)b_g * K2P + h_g] = hb;
        h1nxt[(size_t)b_g * HP + h_g] = hb;
    }
}

// ---------------- step GEMM (r7-verified), frag-pipelined ----------------
__global__ __launch_bounds__(512, 4) void gemm_s128(
    const short* __restrict__ A0, const short* __restrict__ A1, int splitA, int lda,
    const short* __restrict__ Bw, int ldb,
    float* __restrict__ C, long long partStride, int ldc, int nk)
{
    __shared__ __align__(16) short smem[PD][8192];
    const int tid  = threadIdx.x;
    const int lane = tid & 63;
    const int w    = tid >> 6;
    const int wm = w >> 2, wn = w & 3;
    const int tm = blockIdx.y * 128;
    const int tn = blockIdx.x * 128;
    const int s0 = (int)(((long long)nk * blockIdx.z) / gridDim.z);
    const int s1 = (int)(((long long)nk * (blockIdx.z + 1)) / gridDim.z);

    const int rA = tid >> 2, slA = tid & 3;
    const int swz = (slA ^ ((rA >> 1) & 3)) << 3;
    const size_t aoff = (size_t)(tm + rA) * lda + (size_t)swz;
    const size_t boff = (size_t)(tn + rA) * ldb + (size_t)swz;

    auto stage = [&](int buf, int s) {
        const int k0 = s << 5;
        const short* As = (k0 < splitA) ? A0 : A1;
        const short* l = &smem[buf][0];
        gload16(As + k0 + aoff, l + tid * 8);
        gload16(Bw + k0 + boff, l + 4096 + tid * 8);
    };

    const int fr = lane & 15;
    const int kg = lane >> 4;
    int aRd[4], bRd[2];
    #pragma unroll
    for (int mi = 0; mi < 4; ++mi) {
        int row = wm * 64 + mi * 16 + fr;
        aRd[mi] = row * 32 + ((kg ^ ((row >> 1) & 3)) << 3);
    }
    #pragma unroll
    for (int ni = 0; ni < 2; ++ni) {
        int row = wn * 32 + ni * 16 + fr;
        bRd[ni] = 4096 + row * 32 + ((kg ^ ((row >> 1) & 3)) << 3);
    }

    f32x4 acc[4][2];
    #pragma unroll
    for (int a = 0; a < 4; ++a)
        #pragma unroll
        for (int b = 0; b < 2; ++b)
            acc[a][b] = (f32x4){0.f, 0.f, 0.f, 0.f};

    #pragma unroll
    for (int i = 0; i < PD; ++i)
        if (s0 + i < s1) stage(i, s0 + i);

    {
        int ahead = s1 - 1 - s0; if (ahead > PD - 1) ahead = PD - 1;
        if (ahead >= 2)      asm volatile("s_waitcnt vmcnt(4)" ::: "memory");
        else if (ahead == 1) asm volatile("s_waitcnt vmcnt(2)" ::: "memory");
        else                 asm volatile("s_waitcnt vmcnt(0)" ::: "memory");
    }
    __builtin_amdgcn_s_barrier();
    short8 af[4], bf[2];
    {
        const short* bp = &smem[0][0];
        #pragma unroll
        for (int i = 0; i < 4; ++i) af[i] = *(const short8*)(bp + aRd[i]);
        #pragma unroll
        for (int i = 0; i < 2; ++i) bf[i] = *(const short8*)(bp + bRd[i]);
    }

    int buf = 0;
    for (int s = s0; s < s1; ++s) {
        asm volatile("s_waitcnt lgkmcnt(0)" ::: "memory");
        __builtin_amdgcn_sched_barrier(0);
        __builtin_amdgcn_s_barrier();                        // all waves done reading smem[buf]
        if (s + PD < s1) stage(buf, s + PD);
        const int nbuf = (buf + 1 == PD) ? 0 : buf + 1;
        short8 naf[4], nbf[2];
        const bool more = (s + 1 < s1);
        if (more) {
            int ahead = s1 - 1 - (s + 1); if (ahead > PD - 1) ahead = PD - 1;
            if (ahead >= 2)      asm volatile("s_waitcnt vmcnt(4)" ::: "memory");
            else if (ahead == 1) asm volatile("s_waitcnt vmcnt(2)" ::: "memory");
            else                 asm volatile("s_waitcnt vmcnt(0)" ::: "memory");
            __builtin_amdgcn_s_barrier();                    // smem[nbuf] staged
            const short* np = &smem[nbuf][0];
            #pragma unroll
            for (int i = 0; i < 4; ++i) naf[i] = *(const short8*)(np + aRd[i]);
            #pragma unroll
            for (int i = 0; i < 2; ++i) nbf[i] = *(const short8*)(np + bRd[i]);
            __builtin_amdgcn_sched_barrier(0);               // reads issued before MFMAs
        }
        #pragma unroll
        for (int mi = 0; mi < 4; ++mi)
            #pragma unroll
            for (int ni = 0; ni < 2; ++ni)
                acc[mi][ni] = __builtin_amdgcn_mfma_f32_16x16x32_bf16(af[mi], bf[ni], acc[mi][ni], 0, 0, 0);
        if (more) {
            #pragma unroll
            for (int i = 0; i < 4; ++i) af[i] = naf[i];
            #pragma unroll
            for (int i = 0; i < 2; ++i) bf[i] = nbf[i];
        }
        buf = nbuf;
    }

    float* Cp = C + (size_t)partStride * blockIdx.z;
    const int colb = tn + wn * 32 + fr;
    const int rowb = tm + wm * 64 + (kg << 2);
    #pragma unroll
    for (int mi = 0; mi < 4; ++mi)
        #pragma unroll
        for (int ni = 0; ni < 2; ++ni) {
            int col = colb + ni * 16;
            int row0 = rowb + mi * 16;
            #pragma unroll
            for (int j = 0; j < 4; ++j)
                Cp[(size_t)(row0 + j) * ldc + col] = acc[mi][ni][j];
        }
}

// ---------------- logits GEMM + batch-axis softmax (r6-verified), frag-pipelined ------
__global__ __launch_bounds__(512) void logits_sm(
    const short* __restrict__ A /*h2pad*/, const short* __restrict__ Bw /*outwb*/,
    const float* __restrict__ outb, float* __restrict__ out,
    short* __restrict__ z2, int t)
{
    __shared__ __align__(16) short smem[PD][10240];
    __shared__ float red[256];
    const int tid  = threadIdx.x;
    const int lane = tid & 63;
    const int w    = tid >> 6;
    const int wm = w >> 1, wn = w & 1;
    const int tn = blockIdx.x * 64;
    const int nk = HP / 32;                            // 32

    const int cA0 = w * 64 + lane;
    const int cA1 = cA0 + 512;
    const int rA0 = cA0 >> 2, rA1 = cA1 >> 2;
    const size_t aoff0 = (size_t)rA0 * HP + (size_t)((((cA0 & 3) ^ ((rA0 >> 1) & 3))) << 3);
    const size_t aoff1 = (size_t)rA1 * HP + (size_t)((((cA1 & 3) ^ ((rA1 >> 1) & 3))) << 3);
    const int cB = w * 32 + (lane & 31);
    const int rB = cB >> 2;
    const size_t boff = (size_t)(tn + rB) * HP + (size_t)((((cB & 3) ^ ((rB >> 1) & 3))) << 3);

    auto stage = [&](int buf, int s) {
        const int k0 = s << 5;
        const short* l = &smem[buf][0];
        gload16(A + k0 + aoff0, l + w * 512);
        gload16(A + k0 + aoff1, l + 4096 + w * 512);
        if (lane < 32) gload16(Bw + k0 + boff, l + 8192 + w * 256);
    };

    const int fr = lane & 15;
    const int kg = lane >> 4;
    int aRd[4], bRd[2];
    #pragma unroll
    for (int mi = 0; mi < 4; ++mi) {
        int row = wm * 64 + mi * 16 + fr;
        aRd[mi] = row * 32 + ((kg ^ ((row >> 1) & 3)) << 3);
    }
    #pragma unroll
    for (int ni = 0; ni < 2; ++ni) {
        int row = wn * 32 + ni * 16 + fr;
        bRd[ni] = 8192 + row * 32 + ((kg ^ ((row >> 1) & 3)) << 3);
    }

    f32x4 acc[4][2];
    #pragma unroll
    for (int a = 0; a < 4; ++a)
        #pragma unroll
        for (int b = 0; b < 2; ++b)
            acc[a][b] = (f32x4){0.f, 0.f, 0.f, 0.f};

    #pragma unroll
    for (int i = 0; i < PD; ++i) stage(i, i);

    asm volatile("s_waitcnt vmcnt(6)" ::: "memory");   // nk=32 >= PD
    __builtin_amdgcn_s_barrier();
    short8 af[4], bf[2];
    {
        const short* bp = &smem[0][0];
        #pragma unroll
        for (int i = 0; i < 4; ++i) af[i] = *(const short8*)(bp + aRd[i]);
        #pragma unroll
        for (int i = 0; i < 2; ++i) bf[i] = *(const short8*)(bp + bRd[i]);
    }

    int buf = 0;
    for (int s = 0; s < nk; ++s) {
        asm volatile("s_waitcnt lgkmcnt(0)" ::: "memory");
        __builtin_amdgcn_sched_barrier(0);
        __builtin_amdgcn_s_barrier();
        if (s + PD < nk) stage(buf, s + PD);
        const int nbuf = (buf + 1 == PD) ? 0 : buf + 1;
        short8 naf[4], nbf[2];
        const bool more = (s + 1 < nk);
        if (more) {
            int ahead = nk - 1 - (s + 1); if (ahead > PD - 1) ahead = PD - 1;
            if (ahead >= 2)      asm volatile("s_waitcnt vmcnt(6)" ::: "memory");
            else if (ahead == 1) asm volatile("s_waitcnt vmcnt(3)" ::: "memory");
            else                 asm volatile("s_waitcnt vmcnt(0)" ::: "memory");
            __builtin_amdgcn_s_barrier();
            const short* np = &smem[nbuf][0];
            #pragma unroll
            for (int i = 0; i < 4; ++i) naf[i] = *(const short8*)(np + aRd[i]);
            #pragma unroll
            for (int i = 0; i < 2; ++i) nbf[i] = *(const short8*)(np + bRd[i]);
            __builtin_amdgcn_sched_barrier(0);
        }
        #pragma unroll
        for (int mi = 0; mi < 4; ++mi)
            #pragma unroll
            for (int ni = 0; ni < 2; ++ni)
                acc[mi][ni] = __builtin_amdgcn_mfma_f32_16x16x32_bf16(af[mi], bf[ni], acc[mi][ni], 0, 0, 0);
        if (more) {
            #pragma unroll
            for (int i = 0; i < 4; ++i) af[i] = naf[i];
            #pragma unroll
            for (int i = 0; i < 2; ++i) bf[i] = nbf[i];
        }
        buf = nbuf;
    }

    int   colv[2];
    float bv[2];
    #pragma unroll
    for (int ni = 0; ni < 2; ++ni) {
        colv[ni] = tn + wn * 32 + ni * 16 + fr;
        bv[ni] = (colv[ni] < DICT) ? outb[colv[ni]] : 0.f;
    }
    float v[4][2][4];
    float mx[2] = {-3e38f, -3e38f};
    #pragma unroll
    for (int mi = 0; mi < 4; ++mi)
        #pragma unroll
        for (int ni = 0; ni < 2; ++ni)
            #pragma unroll
            for (int j = 0; j < 4; ++j) {
                float x = acc[mi][ni][j] + bv[ni];
                v[mi][ni][j] = x;
                mx[ni] = fmaxf(mx[ni], x);
            }
    #pragma unroll
    for (int ni = 0; ni < 2; ++ni) {
        mx[ni] = fmaxf(mx[ni], __shfl_xor(mx[ni], 16));
        mx[ni] = fmaxf(mx[ni], __shfl_xor(mx[ni], 32));
    }
    if (lane < 16) {
        red[wm * 64 + wn * 32 + fr]      = mx[0];
        red[wm * 64 + wn * 32 + 16 + fr] = mx[1];
    }
    __syncthreads();
    float m[2];
    #pragma unroll
    for (int ni = 0; ni < 2; ++ni) {
        int cc = wn * 32 + ni * 16 + fr;
        m[ni] = fmaxf(fmaxf(red[cc], red[64 + cc]), fmaxf(red[128 + cc], red[192 + cc]));
    }
    __syncthreads();
    float s2[2] = {0.f, 0.f};
    #pragma unroll
    for (int mi = 0; mi < 4; ++mi)
        #pragma unroll
        for (int ni = 0; ni < 2; ++ni)
            #pragma unroll
            for (int j = 0; j < 4; ++j) {
                float e = expf(v[mi][ni][j] - m[ni]);
                v[mi][ni][j] = e;
                s2[ni] += e;
            }
    #pragma unroll
    for (int ni = 0; ni < 2; ++ni) {
        s2[ni] += __shfl_xor(s2[ni], 16);
        s2[ni] += __shfl_xor(s2[ni], 32);
    }
    if (lane < 16) {
        red[wm * 64 + wn * 32 + fr]      = s2[0];
        red[wm * 64 + wn * 32 + 16 + fr] = s2[1];
    }
    __syncthreads();
    float inv[2];
    #pragma unroll
    for (int ni = 0; ni < 2; ++ni) {
        int cc = wn * 32 + ni * 16 + fr;
        inv[ni] = 1.f / (red[cc] + red[64 + cc] + red[128 + cc] + red[192 + cc]);
    }
    const int rowb = wm * 64 + (kg << 2);
    #pragma unroll
    for (int mi = 0; mi < 4; ++mi)
        #pragma unroll
        for (int j = 0; j < 4; ++j) {
            int b = rowb + mi * 16 + j;
            #pragma unroll
            for (int ni = 0; ni < 2; ++ni) {
                if (colv[ni] < DICT) {
                    float y = v[mi][ni][j] * inv[ni];
                    out[(size_t)b * ((size_t)TT * DICT) + (size_t)t * DICT + colv[ni]] = y;
                    z2[(size_t)b * K2P + colv[ni]] = f2b(y);
                }
            }
        }
}

// ---------------- LSTM elementwise (r7-verified): sum NP K-split parts ----------
template <int NP>
__global__ void lstm_ewN(const float* __restrict__ g, long long ps,
                         const float* __restrict__ bias, float* __restrict__ c,
                         short* __restrict__ d1, int ld1,
                         short* __restrict__ d2, int ld2)
{
    int i = blockIdx.x * blockDim.x + threadIdx.x;
    if (i >= BB * HID) return;
    int b = i / HID, h = i % HID;
    size_t base = (size_t)b * G4P + h;
    float gi = bias[h], gf = bias[HID + h], gg = bias[2 * HID + h], go = bias[3 * HID + h];
    #pragma unroll
    for (int p = 0; p < NP; ++p) {
        const float* gp = g + (size_t)ps * p + base;
        gi += gp[0];
        gf += gp[HID];
        gg += gp[2 * HID];
        go += gp[3 * HID];
    }
    float ii = 1.f / (1.f + expf(-gi));
    float ff = 1.f / (1.f + expf(-gf));
    float tg = tanhf(gg);
    float oo = 1.f / (1.f + expf(-go));
    float cn = ff * c[i] + ii * tg;
    c[i] = cn;
    float hn = oo * tanhf(cn);
    short hb = f2b(hn);
    d1[(size_t)b * ld1 + h] = hb;
    d2[(size_t)b * ld2 + h] = hb;
}

// ---------------- host ----------------
extern "C" void kernel_launch(void* const* d_in, const int* in_sizes, int n_in,
                              void* d_out, int out_size, void* d_ws, size_t ws_size,
                              hipStream_t stream)
{
    const float* x    = (const float*)d_in[0];
    const float* h1   = (const float*)d_in[1];
    const float* h2   = (const float*)d_in[2];
    const float* c1in = (const float*)d_in[3];
    const float* c2in = (const float*)d_in[4];
    const float* layW = (const float*)d_in[5];
    const float* layb = (const float*)d_in[6];
    const float* Wih1 = (const float*)d_in[7];
    const float* Whh1 = (const float*)d_in[8];
    const float* bih1 = (const float*)d_in[9];
    const float* bhh1 = (const float*)d_in[10];
    const float* Wih2 = (const float*)d_in[11];
    const float* Whh2 = (const float*)d_in[12];
    const float* bih2 = (const float*)d_in[13];
    const float* bhh2 = (const float*)d_in[14];
    const float* outW = (const float*)d_in[15];
    const float* outb = (const float*)d_in[16];
    float* out = (float*)d_out;
    (void)in_sizes; (void)n_in; (void)out_size; (void)ws_size;

    char* ws = (char*)d_ws;
    size_t off = 0;
    auto alloc = [&](size_t bytes) -> void* {
        size_t p = off;
        off = (off + bytes + 255) & ~(size_t)255;
        return (void*)(ws + p);
    };

    short* w1i   = (short*)alloc((size_t)G4P * K1P * 2);
    short* w2cat = (short*)alloc((size_t)G4P * K2P * 2);
    short* outwb = (short*)alloc((size_t)4864 * HP * 2);
    short* laywb = (short*)alloc((size_t)HID * HID * 2);
    short* xp    = (short*)alloc((size_t)TT * BB * HP * 2);
    short* h1A   = (short*)alloc((size_t)BB * HP * 2);
    short* h1B   = (short*)alloc((size_t)BB * HP * 2);
    short* h2pad = (short*)alloc((size_t)BB * HP * 2);
    short* z2    = (short*)alloc((size_t)BB * K2P * 2);
    float* gbuf  = (float*)alloc((size_t)8 * BB * G4P * 4);
    float* c1    = (float*)alloc((size_t)BB * HID * 4);
    float* c2    = (float*)alloc((size_t)BB * HID * 4);
    float* bi1   = (float*)alloc((size_t)G4P * 4);
    float* bias2 = (float*)alloc((size_t)G4 * 4);

    hipMemsetAsync(xp, 0, (size_t)TT * BB * HP * 2, stream);
    hipMemsetAsync(z2, 0, (size_t)BB * K2P * 2, stream);
    hipMemsetAsync(h1A, 0, (size_t)BB * HP * 2, stream);
    hipMemsetAsync(h1B, 0, (size_t)BB * HP * 2, stream);
    hipMemsetAsync(h2pad, 0, (size_t)BB * HP * 2, stream);

    prep_w1i<<<4096, 256, 0, stream>>>(Wih1, Whh1, w1i);
    prep_w2p<<<dim3(27, G4P), 256, 0, stream>>>(Wih2, Whh2, w2cat);
    prep_outwp<<<dim3(4, 4864), 256, 0, stream>>>(outW, outwb);
    prep_cvt<<<1024, 256, 0, stream>>>(layW, laywb, (size_t)HID * HID);
    prep_biasi<<<16, 256, 0, stream>>>(bih1, bhh1, bi1);
    prep_addv<<<16, 256, 0, stream>>>(bih2, bhh2, bias2, G4);
    init_vec<<<1000, 256, 0, stream>>>(h1, h1A, HP);
    init_vec<<<1000, 256, 0, stream>>>(h2, h2pad, HP);
    init_vec<<<1000, 256, 0, stream>>>(h2, z2 + Z2_H2, K2P);
    hipMemcpyAsync(c1, c1in, (size_t)BB * HID * 4, hipMemcpyDeviceToDevice, stream);
    hipMemcpyAsync(c2, c2in, (size_t)BB * HID * 4, hipMemcpyDeviceToDevice, stream);

    // input projection -> xp[t][b][0:1000] (bf16, stride 1024, pads stay zero)
    gemm_nt<1, 1><<<dim3(16, (BB * TT) / 64, 1), 256, 0, stream>>>(
        x, HID, laywb, HID, layb, xp, 0, HP, BB * TT, HID, HID);

    for (int t = 0; t < TT; ++t) {
        short* hcur = (t & 1) ? h1B : h1A;
        short* hnxt = (t & 1) ? h1A : h1B;

        // gates1(t) + in-block LSTM cell -> h1(t+1) into {z2.h1n, hnxt}, c1 updated
        gates1F<<<dim3(64, 4), 256, 0, stream>>>(
            xp + (size_t)t * BB * HP, hcur - HP, w1i,
            (const f32x4*)bi1, c1, z2 + Z2_H1, hnxt);

        // gates2 = z2 @ w2cat^T  (K-split 8 -> 512 blocks, 2 blocks/CU)
        gemm_s128<<<dim3(32, 2, 8), 512, 0, stream>>>(
            z2, z2, 0, K2P, w2cat, K2P, gbuf, GPART, G4P, K2P / 32);
        lstm_ewN<8><<<1000, 256, 0, stream>>>(
            gbuf, GPART, bias2, c2, z2 + Z2_H2, K2P, h2pad, HP);

        // logits(t) + batch-softmax -> out, z2.prev
        logits_sm<<<76, 512, 0, stream>>>(h2pad, outwb, outb, out, z2, t);
    }
}

// Round 11
// 3385.072 us; speedup vs baseline: 1.1660x; 1.1660x over previous
//
#include <hip/hip_runtime.h>
#include <hip/hip_bf16.h>

#define HID   1000
#define DICT  4811
#define TT    44
#define BB    256
#define G4    4000
#define G4P   4096
#define K1P   2048
#define K2P   6912
#define HP    1024
#define Z2_H2 4864
#define Z2_H1 5888
#define PD    3
#define GPART ((long long)BB * G4P)

typedef __attribute__((ext_vector_type(8))) short short8;
typedef __attribute__((ext_vector_type(4))) float f32x4;

__device__ __forceinline__ short f2b(float f) {
    unsigned u = __float_as_uint(f);
    unsigned r = (u + 0x7FFFu + ((u >> 16) & 1u)) >> 16;
    return (short)r;
}

__device__ __forceinline__ void gload16(const void* g, const short* l) {
    __builtin_amdgcn_global_load_lds(
        (const __attribute__((address_space(1))) unsigned int*)g,
        (__attribute__((address_space(3))) unsigned int*)l, 16, 0, 0);
}

// ---------------- prep kernels ----------------
__global__ void prep_w1i(const float* __restrict__ wih1, const float* __restrict__ whh1,
                         short* __restrict__ w) {
    for (size_t i = (size_t)blockIdx.x * blockDim.x + threadIdx.x; i < (size_t)G4P * K1P;
         i += (size_t)gridDim.x * blockDim.x) {
        int n = (int)(i >> 11), j = (int)(i & 2047);
        int h = n >> 2, g = n & 3;
        float v = 0.f;
        if (h < HID) {
            int r = g * HID + h;
            if (j < HID) v = wih1[(size_t)r * 2000 + j];
            else if (j >= 1024 && j < 1024 + HID) {
                int jj = j - 1024;
                v = wih1[(size_t)r * 2000 + HID + jj] + whh1[(size_t)r * HID + jj];
            }
        }
        w[i] = f2b(v);
    }
}

__global__ void prep_w2p(const float* __restrict__ wih2, const float* __restrict__ whh2,
                         short* __restrict__ w) {
    int n = blockIdx.y;
    int j = blockIdx.x * 256 + threadIdx.x;
    float v = 0.f;
    if (n < G4) {
        if (j < DICT) v = wih2[(size_t)n * 6811 + j];
        else if (j >= Z2_H2 && j < Z2_H2 + HID) {
            int jj = j - Z2_H2;
            v = wih2[(size_t)n * 6811 + DICT + jj] + whh2[(size_t)n * HID + jj];
        } else if (j >= Z2_H1 && j < Z2_H1 + HID) {
            int jj = j - Z2_H1;
            v = wih2[(size_t)n * 6811 + DICT + HID + jj];
        }
    }
    w[(size_t)n * K2P + j] = f2b(v);
}

__global__ void prep_outwp(const float* __restrict__ outw, short* __restrict__ w) {
    int n = blockIdx.y;
    int j = blockIdx.x * 256 + threadIdx.x;
    float v = (n < DICT && j < HID) ? outw[(size_t)n * HID + j] : 0.f;
    w[(size_t)n * HP + j] = f2b(v);
}

__global__ void prep_cvt(const float* __restrict__ src, short* __restrict__ dst, size_t n) {
    for (size_t i = (size_t)blockIdx.x * blockDim.x + threadIdx.x; i < n;
         i += (size_t)gridDim.x * blockDim.x)
        dst[i] = f2b(src[i]);
}

__global__ void prep_addv(const float* __restrict__ a, const float* __restrict__ b,
                          float* __restrict__ dst, int n) {
    int i = blockIdx.x * blockDim.x + threadIdx.x;
    if (i < n) dst[i] = a[i] + b[i];
}

__global__ void prep_biasi(const float* __restrict__ bi, const float* __restrict__ bh,
                           float* __restrict__ dst) {
    int n = blockIdx.x * 256 + threadIdx.x;
    if (n >= 4096) return;
    int h = n >> 2, g = n & 3;
    dst[n] = (h < HID) ? bi[g * HID + h] + bh[g * HID + h] : 0.f;
}

__global__ void init_vec(const float* __restrict__ src, short* __restrict__ dst, int ld) {
    int i = blockIdx.x * blockDim.x + threadIdx.x;
    if (i >= BB * HID) return;
    int b = i / HID, h = i % HID;
    dst[(size_t)b * ld + h] = f2b(src[i]);
}

// ---------------- xp projection GEMM (verified, runs once) ----------------
template <int EPI, int AF32>
__global__ __launch_bounds__(256) void gemm_nt(
    const void* __restrict__ Ap, int lda,
    const short* __restrict__ Bp, int ldb,
    const float* __restrict__ bias,
    void* __restrict__ Cp, long long partStride, int ldc,
    int M, int N, int Kvalid)
{
    __shared__ short As[64][40];
    __shared__ short Bs[64][40];
    const int tid  = threadIdx.x;
    const int lane = tid & 63;
    const int wave = tid >> 6;
    const int wm = wave >> 1, wn = wave & 1;
    const int tm = blockIdx.y * 64, tn = blockIdx.x * 64;
    const int srow = tid >> 2;
    const int scol = (tid & 3) * 8;

    const int nk = (Kvalid + 31) >> 5;
    const int s0 = (int)(((long long)nk * blockIdx.z) / gridDim.z);
    const int s1 = (int)(((long long)nk * (blockIdx.z + 1)) / gridDim.z);

    const int arow = tm + srow;
    const int brow = tn + srow;
    const bool bvalid = brow < N;

    auto loadA = [&](int ks) -> short8 {
        int k = (ks << 5) + scol;
        short8 r = {0, 0, 0, 0, 0, 0, 0, 0};
        if (k + 8 <= Kvalid) {
            if (AF32) {
                const f32x4* p = (const f32x4*)((const float*)Ap + (size_t)arow * lda + k);
                f32x4 u0 = p[0], u1 = p[1];
                r[0] = f2b(u0[0]); r[1] = f2b(u0[1]); r[2] = f2b(u0[2]); r[3] = f2b(u0[3]);
                r[4] = f2b(u1[0]); r[5] = f2b(u1[1]); r[6] = f2b(u1[2]); r[7] = f2b(u1[3]);
            } else {
                r = *(const short8*)((const short*)Ap + (size_t)arow * lda + k);
            }
        }
        return r;
    };
    auto loadB = [&](int ks) -> short8 {
        int k = (ks << 5) + scol;
        short8 r = {0, 0, 0, 0, 0, 0, 0, 0};
        if (bvalid && (k + 8 <= Kvalid))
            r = *(const short8*)(Bp + (size_t)brow * ldb + k);
        return r;
    };

    f32x4 acc[2][2];
    for (int a = 0; a < 2; ++a)
        for (int b = 0; b < 2; ++b)
            acc[a][b] = (f32x4){0.f, 0.f, 0.f, 0.f};

    short8 ra = loadA(s0), rb = loadB(s0);
    *(short8*)&As[srow][scol] = ra;
    *(short8*)&Bs[srow][scol] = rb;
    __syncthreads();

    const int kg = (lane >> 4) * 8;
    const int fr = lane & 15;

    for (int s = s0; s < s1; ++s) {
        short8 a0 = *(short8*)&As[wm * 32 + fr][kg];
        short8 a1 = *(short8*)&As[wm * 32 + 16 + fr][kg];
        short8 b0 = *(short8*)&Bs[wn * 32 + fr][kg];
        short8 b1 = *(short8*)&Bs[wn * 32 + 16 + fr][kg];
        short8 na, nb;
        if (s + 1 < s1) { na = loadA(s + 1); nb = loadB(s + 1); }
        acc[0][0] = __builtin_amdgcn_mfma_f32_16x16x32_bf16(a0, b0, acc[0][0], 0, 0, 0);
        acc[0][1] = __builtin_amdgcn_mfma_f32_16x16x32_bf16(a0, b1, acc[0][1], 0, 0, 0);
        acc[1][0] = __builtin_amdgcn_mfma_f32_16x16x32_bf16(a1, b0, acc[1][0], 0, 0, 0);
        acc[1][1] = __builtin_amdgcn_mfma_f32_16x16x32_bf16(a1, b1, acc[1][1], 0, 0, 0);
        __syncthreads();
        if (s + 1 < s1) {
            *(short8*)&As[srow][scol] = na;
            *(short8*)&Bs[srow][scol] = nb;
        }
        __syncthreads();
    }

    float* Cf = (float*)Cp + (size_t)partStride * blockIdx.z;
    for (int mi = 0; mi < 2; ++mi)
        for (int ni = 0; ni < 2; ++ni) {
            int col = tn + wn * 32 + ni * 16 + (lane & 15);
            if (col >= N) continue;
            float bv = bias ? bias[col] : 0.f;
            int row0 = tm + wm * 32 + mi * 16 + ((lane >> 4) << 2);
            f32x4 v = acc[mi][ni];
            for (int j = 0; j < 4; ++j) {
                int row = row0 + j;
                float val = v[j] + bv;
                if (EPI == 0) {
                    Cf[(size_t)row * ldc + col] = val;
                } else {
                    int b = row / TT, t = row % TT;
                    ((short*)Cp)[((size_t)t * BB + b) * ldc + col] = f2b(val);
                }
            }
        }
}

// ---------------- gates1 GEMM + in-block LSTM cell (r9-verified body) ----------------
__device__ __forceinline__ void gates1F_dev(short* smem, int bx, int by,
    const short* __restrict__ xp_t,
    const short* __restrict__ h1m,
    const short* __restrict__ w1i,
    const f32x4* __restrict__ bias4,
    float* __restrict__ c1,
    short* __restrict__ zh1,
    short* __restrict__ h1nxt)
{
    const int tid  = threadIdx.x;
    const int lane = tid & 63;
    const int w    = tid >> 6;
    const int wm = w >> 1, wn = w & 1;
    const int tm = by * 64;
    const int tn = bx * 64;
    const int nk = K1P / 32;                          // 64

    const int rA = tid >> 2, sl = tid & 3;
    const int swz = (sl ^ ((rA >> 1) & 3)) << 3;
    const size_t aoff = (size_t)(tm + rA) * HP + (size_t)swz;
    const size_t boff = (size_t)(tn + rA) * K1P + (size_t)swz;

    auto stage = [&](int buf, int s) {
        const int k0 = s << 5;
        const short* As = (k0 < 1024) ? xp_t : h1m;
        const short* l = smem + buf * 4096;
        gload16(As + k0 + aoff, l + tid * 8);
        gload16(w1i + k0 + boff, l + 2048 + tid * 8);
    };

    const int fr = lane & 15;
    const int kg = lane >> 4;
    int aRd[2], bRd[2];
    #pragma unroll
    for (int mi = 0; mi < 2; ++mi) {
        int row = wm * 32 + mi * 16 + fr;
        aRd[mi] = row * 32 + ((kg ^ ((row >> 1) & 3)) << 3);
    }
    #pragma unroll
    for (int ni = 0; ni < 2; ++ni) {
        int row = wn * 32 + ni * 16 + fr;
        bRd[ni] = 2048 + row * 32 + ((kg ^ ((row >> 1) & 3)) << 3);
    }

    f32x4 acc[2][2];
    #pragma unroll
    for (int a = 0; a < 2; ++a)
        #pragma unroll
        for (int b = 0; b < 2; ++b)
            acc[a][b] = (f32x4){0.f, 0.f, 0.f, 0.f};

    #pragma unroll
    for (int i = 0; i < PD; ++i) stage(i, i);

    int buf = 0;
    for (int s = 0; s < nk; ++s) {
        const int ahead = nk - 1 - s;
        if (ahead >= 2)      asm volatile("s_waitcnt vmcnt(4)" ::: "memory");
        else if (ahead == 1) asm volatile("s_waitcnt vmcnt(2)" ::: "memory");
        else                 asm volatile("s_waitcnt vmcnt(0)" ::: "memory");
        __builtin_amdgcn_s_barrier();

        const short* bp = smem + buf * 4096;
        short8 af[2], bf[2];
        #pragma unroll
        for (int i = 0; i < 2; ++i) af[i] = *(const short8*)(bp + aRd[i]);
        #pragma unroll
        for (int i = 0; i < 2; ++i) bf[i] = *(const short8*)(bp + bRd[i]);
        asm volatile("s_waitcnt lgkmcnt(0)" ::: "memory");
        __builtin_amdgcn_sched_barrier(0);
        __builtin_amdgcn_s_barrier();
        if (s + PD < nk) stage(buf, s + PD);

        #pragma unroll
        for (int mi = 0; mi < 2; ++mi)
            #pragma unroll
            for (int ni = 0; ni < 2; ++ni)
                acc[mi][ni] = __builtin_amdgcn_mfma_f32_16x16x32_bf16(af[mi], bf[ni], acc[mi][ni], 0, 0, 0);

        buf = (buf + 1 == PD) ? 0 : buf + 1;
    }

    // epilogue: acc -> LDS [64][68] f32, then LSTM cell (single writer)
    float* gl = (float*)smem;
    #pragma unroll
    for (int mi = 0; mi < 2; ++mi)
        #pragma unroll
        for (int ni = 0; ni < 2; ++ni) {
            int row = wm * 32 + mi * 16 + kg * 4;
            int col = wn * 32 + ni * 16 + fr;
            #pragma unroll
            for (int j = 0; j < 4; ++j)
                gl[(row + j) * 68 + col] = acc[mi][ni][j];
        }
    __syncthreads();

    const int b_loc = tid & 63;
    const int b_g = tm + b_loc;
    #pragma unroll
    for (int q = 0; q < 4; ++q) {
        int h_loc = (tid >> 6) * 4 + q;
        int h_g = bx * 16 + h_loc;
        if (h_g >= HID) continue;
        f32x4 g4 = *(const f32x4*)(gl + b_loc * 68 + h_loc * 4);
        g4 += bias4[h_g];
        float ii = 1.f / (1.f + expf(-g4[0]));
        float ff = 1.f / (1.f + expf(-g4[1]));
        float tg = tanhf(g4[2]);
        float oo = 1.f / (1.f + expf(-g4[3]));
        float cn = ff * c1[(size_t)b_g * HID + h_g] + ii * tg;
        c1[(size_t)b_g * HID + h_g] = cn;
        short hb = f2b(oo * tanhf(cn));
        zh1[(size_t)b_g * K2P + h_g] = hb;
        h1nxt[(size_t)b_g * HP + h_g] = hb;
    }
}

__global__ __launch_bounds__(256) void gates1F(
    const short* __restrict__ xp_t, const short* __restrict__ h1m,
    const short* __restrict__ w1i, const f32x4* __restrict__ bias4,
    float* __restrict__ c1, short* __restrict__ zh1, short* __restrict__ h1nxt)
{
    __shared__ __align__(16) short smem[PD * 4096];
    gates1F_dev(smem, blockIdx.x, blockIdx.y, xp_t, h1m, w1i, bias4, c1, zh1, h1nxt);
}

// ---------------- LSTM-2 elementwise body (r7-verified, NP=8) ----------------
__device__ __forceinline__ void lstm2_dev(int blk,
    const float* __restrict__ g, const float* __restrict__ bias, float* __restrict__ c,
    short* __restrict__ d1, int ld1, short* __restrict__ d2, int ld2)
{
    int i = blk * 256 + threadIdx.x;
    if (i >= BB * HID) return;
    int b = i / HID, h = i % HID;
    size_t base = (size_t)b * G4P + h;
    float gi = bias[h], gf = bias[HID + h], gg = bias[2 * HID + h], go = bias[3 * HID + h];
    #pragma unroll
    for (int p = 0; p < 8; ++p) {
        const float* gp = g + (size_t)GPART * p + base;
        gi += gp[0];
        gf += gp[HID];
        gg += gp[2 * HID];
        go += gp[3 * HID];
    }
    float ii = 1.f / (1.f + expf(-gi));
    float ff = 1.f / (1.f + expf(-gf));
    float tg = tanhf(gg);
    float oo = 1.f / (1.f + expf(-go));
    float cn = ff * c[i] + ii * tg;
    c[i] = cn;
    float hn = oo * tanhf(cn);
    short hb = f2b(hn);
    d1[(size_t)b * ld1 + h] = hb;
    d2[(size_t)b * ld2 + h] = hb;
}

// ---------------- fusedC: gates1F(t+1) [blocks 0..255] || lstm2(t) [blocks 256..1255] --
// Write sets disjoint: {z2.h1n, h1nxt, c1} vs {z2.h2, h2pad, c2}. No shared R/W.
__global__ __launch_bounds__(256) void fusedC(
    const short* __restrict__ xp_t1, const short* __restrict__ h1m,
    const short* __restrict__ w1i, const f32x4* __restrict__ bi1,
    float* __restrict__ c1, short* __restrict__ zh1, short* __restrict__ h1nxt,
    const float* __restrict__ gbuf, const float* __restrict__ bias2,
    float* __restrict__ c2, short* __restrict__ zh2, short* __restrict__ h2pad)
{
    __shared__ __align__(16) short smem[PD * 4096];
    const int x = blockIdx.x;
    if (x < 256)
        gates1F_dev(smem, x & 63, x >> 6, xp_t1, h1m, w1i, bi1, c1, zh1, h1nxt);
    else
        lstm2_dev(x - 256, gbuf, bias2, c2, zh2, K2P, h2pad, HP);
}

// ---------------- step GEMM (r7-verified): 128x128 tile, splitK partials --------------
__global__ __launch_bounds__(512, 4) void gemm_s128(
    const short* __restrict__ A0, const short* __restrict__ A1, int splitA, int lda,
    const short* __restrict__ Bw, int ldb,
    float* __restrict__ C, long long partStride, int ldc, int nk)
{
    __shared__ __align__(16) short smem[PD][8192];
    const int tid  = threadIdx.x;
    const int lane = tid & 63;
    const int w    = tid >> 6;
    const int wm = w >> 2, wn = w & 3;
    const int tm = blockIdx.y * 128;
    const int tn = blockIdx.x * 128;
    const int s0 = (int)(((long long)nk * blockIdx.z) / gridDim.z);
    const int s1 = (int)(((long long)nk * (blockIdx.z + 1)) / gridDim.z);

    const int rA = tid >> 2, slA = tid & 3;
    const int swz = (slA ^ ((rA >> 1) & 3)) << 3;
    const size_t aoff = (size_t)(tm + rA) * lda + (size_t)swz;
    const size_t boff = (size_t)(tn + rA) * ldb + (size_t)swz;

    auto stage = [&](int buf, int s) {
        const int k0 = s << 5;
        const short* As = (k0 < splitA) ? A0 : A1;
        const short* l = &smem[buf][0];
        gload16(As + k0 + aoff, l + tid * 8);
        gload16(Bw + k0 + boff, l + 4096 + tid * 8);
    };

    const int fr = lane & 15;
    const int kg = lane >> 4;
    int aRd[4], bRd[2];
    #pragma unroll
    for (int mi = 0; mi < 4; ++mi) {
        int row = wm * 64 + mi * 16 + fr;
        aRd[mi] = row * 32 + ((kg ^ ((row >> 1) & 3)) << 3);
    }
    #pragma unroll
    for (int ni = 0; ni < 2; ++ni) {
        int row = wn * 32 + ni * 16 + fr;
        bRd[ni] = 4096 + row * 32 + ((kg ^ ((row >> 1) & 3)) << 3);
    }

    f32x4 acc[4][2];
    #pragma unroll
    for (int a = 0; a < 4; ++a)
        #pragma unroll
        for (int b = 0; b < 2; ++b)
            acc[a][b] = (f32x4){0.f, 0.f, 0.f, 0.f};

    #pragma unroll
    for (int i = 0; i < PD; ++i)
        if (s0 + i < s1) stage(i, s0 + i);

    int buf = 0;
    for (int s = s0; s < s1; ++s) {
        const int ahead = s1 - 1 - s;
        if (ahead >= 2)      asm volatile("s_waitcnt vmcnt(4)" ::: "memory");
        else if (ahead == 1) asm volatile("s_waitcnt vmcnt(2)" ::: "memory");
        else                 asm volatile("s_waitcnt vmcnt(0)" ::: "memory");
        __builtin_amdgcn_s_barrier();

        const short* bp = &smem[buf][0];
        short8 af[4], bf[2];
        #pragma unroll
        for (int i = 0; i < 4; ++i) af[i] = *(const short8*)(bp + aRd[i]);
        #pragma unroll
        for (int i = 0; i < 2; ++i) bf[i] = *(const short8*)(bp + bRd[i]);
        asm volatile("s_waitcnt lgkmcnt(0)" ::: "memory");
        __builtin_amdgcn_sched_barrier(0);
        __builtin_amdgcn_s_barrier();
        if (s + PD < s1) stage(buf, s + PD);

        #pragma unroll
        for (int mi = 0; mi < 4; ++mi)
            #pragma unroll
            for (int ni = 0; ni < 2; ++ni)
                acc[mi][ni] = __builtin_amdgcn_mfma_f32_16x16x32_bf16(af[mi], bf[ni], acc[mi][ni], 0, 0, 0);

        buf = (buf + 1 == PD) ? 0 : buf + 1;
    }

    float* Cp = C + (size_t)partStride * blockIdx.z;
    const int colb = tn + wn * 32 + fr;
    const int rowb = tm + wm * 64 + (kg << 2);
    #pragma unroll
    for (int mi = 0; mi < 4; ++mi)
        #pragma unroll
        for (int ni = 0; ni < 2; ++ni) {
            int col = colb + ni * 16;
            int row0 = rowb + mi * 16;
            #pragma unroll
            for (int j = 0; j < 4; ++j)
                Cp[(size_t)(row0 + j) * ldc + col] = acc[mi][ni][j];
        }
}

// ---------------- logits GEMM + batch-axis softmax, fused (r6-verified) ----------
__global__ __launch_bounds__(512) void logits_sm(
    const short* __restrict__ A /*h2pad*/, const short* __restrict__ Bw /*outwb*/,
    const float* __restrict__ outb, float* __restrict__ out,
    short* __restrict__ z2, int t)
{
    __shared__ __align__(16) short smem[PD][10240];
    __shared__ float red[256];
    const int tid  = threadIdx.x;
    const int lane = tid & 63;
    const int w    = tid >> 6;
    const int wm = w >> 1, wn = w & 1;
    const int tn = blockIdx.x * 64;
    const int nk = HP / 32;

    const int cA0 = w * 64 + lane;
    const int cA1 = cA0 + 512;
    const int rA0 = cA0 >> 2, rA1 = cA1 >> 2;
    const size_t aoff0 = (size_t)rA0 * HP + (size_t)((((cA0 & 3) ^ ((rA0 >> 1) & 3))) << 3);
    const size_t aoff1 = (size_t)rA1 * HP + (size_t)((((cA1 & 3) ^ ((rA1 >> 1) & 3))) << 3);
    const int cB = w * 32 + (lane & 31);
    const int rB = cB >> 2;
    const size_t boff = (size_t)(tn + rB) * HP + (size_t)((((cB & 3) ^ ((rB >> 1) & 3))) << 3);

    auto stage = [&](int buf, int s) {
        const int k0 = s << 5;
        const short* l = &smem[buf][0];
        gload16(A + k0 + aoff0, l + w * 512);
        gload16(A + k0 + aoff1, l + 4096 + w * 512);
        if (lane < 32) gload16(Bw + k0 + boff, l + 8192 + w * 256);
    };

    const int fr = lane & 15;
    const int kg = lane >> 4;
    int aRd[4], bRd[2];
    #pragma unroll
    for (int mi = 0; mi < 4; ++mi) {
        int row = wm * 64 + mi * 16 + fr;
        aRd[mi] = row * 32 + ((kg ^ ((row >> 1) & 3)) << 3);
    }
    #pragma unroll
    for (int ni = 0; ni < 2; ++ni) {
        int row = wn * 32 + ni * 16 + fr;
        bRd[ni] = 8192 + row * 32 + ((kg ^ ((row >> 1) & 3)) << 3);
    }

    f32x4 acc[4][2];
    #pragma unroll
    for (int a = 0; a < 4; ++a)
        #pragma unroll
        for (int b = 0; b < 2; ++b)
            acc[a][b] = (f32x4){0.f, 0.f, 0.f, 0.f};

    #pragma unroll
    for (int i = 0; i < PD; ++i) stage(i, i);

    int buf = 0;
    for (int s = 0; s < nk; ++s) {
        const int ahead = nk - 1 - s;
        if (ahead >= 2)      asm volatile("s_waitcnt vmcnt(6)" ::: "memory");
        else if (ahead == 1) asm volatile("s_waitcnt vmcnt(3)" ::: "memory");
        else                 asm volatile("s_waitcnt vmcnt(0)" ::: "memory");
        __builtin_amdgcn_s_barrier();

        const short* bp = &smem[buf][0];
        short8 af[4], bf[2];
        #pragma unroll
        for (int i = 0; i < 4; ++i) af[i] = *(const short8*)(bp + aRd[i]);
        #pragma unroll
        for (int i = 0; i < 2; ++i) bf[i] = *(const short8*)(bp + bRd[i]);
        asm volatile("s_waitcnt lgkmcnt(0)" ::: "memory");
        __builtin_amdgcn_sched_barrier(0);
        __builtin_amdgcn_s_barrier();
        if (s + PD < nk) stage(buf, s + PD);

        #pragma unroll
        for (int mi = 0; mi < 4; ++mi)
            #pragma unroll
            for (int ni = 0; ni < 2; ++ni)
                acc[mi][ni] = __builtin_amdgcn_mfma_f32_16x16x32_bf16(af[mi], bf[ni], acc[mi][ni], 0, 0, 0);

        buf = (buf + 1 == PD) ? 0 : buf + 1;
    }

    int   colv[2];
    float bv[2];
    #pragma unroll
    for (int ni = 0; ni < 2; ++ni) {
        colv[ni] = tn + wn * 32 + ni * 16 + fr;
        bv[ni] = (colv[ni] < DICT) ? outb[colv[ni]] : 0.f;
    }
    float v[4][2][4];
    float mx[2] = {-3e38f, -3e38f};
    #pragma unroll
    for (int mi = 0; mi < 4; ++mi)
        #pragma unroll
        for (int ni = 0; ni < 2; ++ni)
            #pragma unroll
            for (int j = 0; j < 4; ++j) {
                float x = acc[mi][ni][j] + bv[ni];
                v[mi][ni][j] = x;
                mx[ni] = fmaxf(mx[ni], x);
            }
    #pragma unroll
    for (int ni = 0; ni < 2; ++ni) {
        mx[ni] = fmaxf(mx[ni], __shfl_xor(mx[ni], 16));
        mx[ni] = fmaxf(mx[ni], __shfl_xor(mx[ni], 32));
    }
    if (lane < 16) {
        red[wm * 64 + wn * 32 + fr]      = mx[0];
        red[wm * 64 + wn * 32 + 16 + fr] = mx[1];
    }
    __syncthreads();
    float m[2];
    #pragma unroll
    for (int ni = 0; ni < 2; ++ni) {
        int cc = wn * 32 + ni * 16 + fr;
        m[ni] = fmaxf(fmaxf(red[cc], red[64 + cc]), fmaxf(red[128 + cc], red[192 + cc]));
    }
    __syncthreads();
    float s2[2] = {0.f, 0.f};
    #pragma unroll
    for (int mi = 0; mi < 4; ++mi)
        #pragma unroll
        for (int ni = 0; ni < 2; ++ni)
            #pragma unroll
            for (int j = 0; j < 4; ++j) {
                float e = expf(v[mi][ni][j] - m[ni]);
                v[mi][ni][j] = e;
                s2[ni] += e;
            }
    #pragma unroll
    for (int ni = 0; ni < 2; ++ni) {
        s2[ni] += __shfl_xor(s2[ni], 16);
        s2[ni] += __shfl_xor(s2[ni], 32);
    }
    if (lane < 16) {
        red[wm * 64 + wn * 32 + fr]      = s2[0];
        red[wm * 64 + wn * 32 + 16 + fr] = s2[1];
    }
    __syncthreads();
    float inv[2];
    #pragma unroll
    for (int ni = 0; ni < 2; ++ni) {
        int cc = wn * 32 + ni * 16 + fr;
        inv[ni] = 1.f / (red[cc] + red[64 + cc] + red[128 + cc] + red[192 + cc]);
    }
    const int rowb = wm * 64 + (kg << 2);
    #pragma unroll
    for (int mi = 0; mi < 4; ++mi)
        #pragma unroll
        for (int j = 0; j < 4; ++j) {
            int b = rowb + mi * 16 + j;
            #pragma unroll
            for (int ni = 0; ni < 2; ++ni) {
                if (colv[ni] < DICT) {
                    float y = v[mi][ni][j] * inv[ni];
                    out[(size_t)b * ((size_t)TT * DICT) + (size_t)t * DICT + colv[ni]] = y;
                    z2[(size_t)b * K2P + colv[ni]] = f2b(y);
                }
            }
        }
}

// ---------------- host ----------------
extern "C" void kernel_launch(void* const* d_in, const int* in_sizes, int n_in,
                              void* d_out, int out_size, void* d_ws, size_t ws_size,
                              hipStream_t stream)
{
    const float* x    = (const float*)d_in[0];
    const float* h1   = (const float*)d_in[1];
    const float* h2   = (const float*)d_in[2];
    const float* c1in = (const float*)d_in[3];
    const float* c2in = (const float*)d_in[4];
    const float* layW = (const float*)d_in[5];
    const float* layb = (const float*)d_in[6];
    const float* Wih1 = (const float*)d_in[7];
    const float* Whh1 = (const float*)d_in[8];
    const float* bih1 = (const float*)d_in[9];
    const float* bhh1 = (const float*)d_in[10];
    const float* Wih2 = (const float*)d_in[11];
    const float* Whh2 = (const float*)d_in[12];
    const float* bih2 = (const float*)d_in[13];
    const float* bhh2 = (const float*)d_in[14];
    const float* outW = (const float*)d_in[15];
    const float* outb = (const float*)d_in[16];
    float* out = (float*)d_out;
    (void)in_sizes; (void)n_in; (void)out_size; (void)ws_size;

    char* ws = (char*)d_ws;
    size_t off = 0;
    auto alloc = [&](size_t bytes) -> void* {
        size_t p = off;
        off = (off + bytes + 255) & ~(size_t)255;
        return (void*)(ws + p);
    };

    short* w1i   = (short*)alloc((size_t)G4P * K1P * 2);
    short* w2cat = (short*)alloc((size_t)G4P * K2P * 2);
    short* outwb = (short*)alloc((size_t)4864 * HP * 2);
    short* laywb = (short*)alloc((size_t)HID * HID * 2);
    short* xp    = (short*)alloc((size_t)TT * BB * HP * 2);
    short* h1A   = (short*)alloc((size_t)BB * HP * 2);
    short* h1B   = (short*)alloc((size_t)BB * HP * 2);
    short* h2pad = (short*)alloc((size_t)BB * HP * 2);
    short* z2    = (short*)alloc((size_t)BB * K2P * 2);
    float* gbuf  = (float*)alloc((size_t)8 * BB * G4P * 4);
    float* c1    = (float*)alloc((size_t)BB * HID * 4);
    float* c2    = (float*)alloc((size_t)BB * HID * 4);
    float* bi1   = (float*)alloc((size_t)G4P * 4);
    float* bias2 = (float*)alloc((size_t)G4 * 4);

    hipMemsetAsync(xp, 0, (size_t)TT * BB * HP * 2, stream);
    hipMemsetAsync(z2, 0, (size_t)BB * K2P * 2, stream);
    hipMemsetAsync(h1A, 0, (size_t)BB * HP * 2, stream);
    hipMemsetAsync(h1B, 0, (size_t)BB * HP * 2, stream);
    hipMemsetAsync(h2pad, 0, (size_t)BB * HP * 2, stream);

    prep_w1i<<<4096, 256, 0, stream>>>(Wih1, Whh1, w1i);
    prep_w2p<<<dim3(27, G4P), 256, 0, stream>>>(Wih2, Whh2, w2cat);
    prep_outwp<<<dim3(4, 4864), 256, 0, stream>>>(outW, outwb);
    prep_cvt<<<1024, 256, 0, stream>>>(layW, laywb, (size_t)HID * HID);
    prep_biasi<<<16, 256, 0, stream>>>(bih1, bhh1, bi1);
    prep_addv<<<16, 256, 0, stream>>>(bih2, bhh2, bias2, G4);
    init_vec<<<1000, 256, 0, stream>>>(h1, h1A, HP);
    init_vec<<<1000, 256, 0, stream>>>(h2, h2pad, HP);
    init_vec<<<1000, 256, 0, stream>>>(h2, z2 + Z2_H2, K2P);
    hipMemcpyAsync(c1, c1in, (size_t)BB * HID * 4, hipMemcpyDeviceToDevice, stream);
    hipMemcpyAsync(c2, c2in, (size_t)BB * HID * 4, hipMemcpyDeviceToDevice, stream);

    // input projection -> xp[t][b][0:1000] (bf16, stride 1024, pads stay zero)
    gemm_nt<1, 1><<<dim3(16, (BB * TT) / 64, 1), 256, 0, stream>>>(
        x, HID, laywb, HID, layb, xp, 0, HP, BB * TT, HID, HID);

    // prologue: gates1F(0) -> h1(1) into {z2.h1n, h1B}, c1 step-0 update
    gates1F<<<dim3(64, 4), 256, 0, stream>>>(
        xp, h1A - HP, w1i, (const f32x4*)bi1, c1, z2 + Z2_H1, h1B);

    for (int t = 0; t < TT; ++t) {
        short* hcur = (t & 1) ? h1A : h1B;   // holds h1(t+1)
        short* hnxt = (t & 1) ? h1B : h1A;
        int tn1 = (t + 1 < TT) ? (t + 1) : (TT - 1);   // t=43: dead in-bounds compute

        // 1) gates2(t) = z2 @ w2cat^T  (K-split 8, 512 blocks, 2/CU)
        gemm_s128<<<dim3(32, 2, 8), 512, 0, stream>>>(
            z2, z2, 0, K2P, w2cat, K2P, gbuf, GPART, G4P, K2P / 32);

        // 2) fusedC: gates1F(t+1) || lstm2(t)
        fusedC<<<1256, 256, 0, stream>>>(
            xp + (size_t)tn1 * BB * HP, hcur - HP, w1i, (const f32x4*)bi1,
            c1, z2 + Z2_H1, hnxt,
            gbuf, bias2, c2, z2 + Z2_H2, h2pad);

        // 3) logits(t) + batch-softmax -> out(t), z2.prev
        logits_sm<<<76, 512, 0, stream>>>(h2pad, outwb, outb, out, z2, t);
    }
}